// Round 2
// baseline (253.685 us; speedup 1.0000x reference)
//
#include <hip/hip_runtime.h>
#include <hip/hip_bf16.h>

typedef __attribute__((ext_vector_type(4))) float f32x4;
typedef __bf16 bf16x8 __attribute__((ext_vector_type(8)));
using bf16 = __hip_bfloat16;

// Problem constants
constexpr int BB = 2, SS = 2048, DDIM = 512, NHEAD = 8, HDIM = 64, MLPD = 2048;
constexpr int NTOK = BB * SS;          // 4096
constexpr int WHALF = 256;             // window // 2
constexpr int NGLOB = 64;
constexpr float NEGBIG = -1e10f;

// Workspace layout (bytes)
constexpr size_t SZ_X1    = (size_t)NTOK * DDIM * 2;
constexpr size_t SZ_WQKVT = (size_t)1536 * DDIM * 2;
constexpr size_t SZ_WOT   = (size_t)DDIM * DDIM * 2;
constexpr size_t SZ_W1T   = (size_t)MLPD * DDIM * 2;
constexpr size_t SZ_W2T   = (size_t)DDIM * MLPD * 2;
constexpr size_t SZ_HEAD  = (size_t)BB * NHEAD * SS * HDIM * 2;  // one of q/k/v
constexpr size_t SZ_QKV   = 3 * SZ_HEAD;
constexpr size_t SZ_CTX   = (size_t)NTOK * DDIM * 2;
constexpr size_t SZ_XRES  = (size_t)NTOK * DDIM * 4;
constexpr size_t SZ_Y1    = (size_t)NTOK * DDIM * 2;

constexpr size_t OFF_X1    = 0;
constexpr size_t OFF_WQKVT = OFF_X1 + SZ_X1;
constexpr size_t OFF_WOT   = OFF_WQKVT + SZ_WQKVT;
constexpr size_t OFF_W1T   = OFF_WOT + SZ_WOT;
constexpr size_t OFF_W2T   = OFF_W1T + SZ_W1T;
constexpr size_t OFF_QKV   = OFF_W2T + SZ_W2T;
constexpr size_t OFF_CTX   = OFF_QKV + SZ_QKV;
constexpr size_t OFF_XRES  = OFF_CTX + SZ_CTX;
constexpr size_t OFF_Y1    = OFF_XRES + SZ_XRES;
constexpr size_t OFF_H1    = OFF_Y1 + SZ_Y1;

// ---------------------------------------------------------------------------
// Transpose + cast fp32 [K][N] -> bf16 [N][K], with scale.
// ---------------------------------------------------------------------------
__global__ void transpose_cast_kernel(const float* __restrict__ in, bf16* __restrict__ out,
                                      int K, int N, float scale) {
  __shared__ __align__(16) bf16 tile[64][65];
  int k0 = blockIdx.y * 64;
  int n0 = blockIdx.x * 64;
  int t = threadIdx.x;
  for (int it = 0; it < 16; ++it) {
    int idx = it * 256 + t;
    int r = idx >> 6, c = idx & 63;                    // r -> k, c -> n (coalesced)
    float v = in[(size_t)(k0 + r) * N + n0 + c] * scale;
    tile[c][r] = __float2bfloat16(v);
  }
  __syncthreads();
  for (int it = 0; it < 16; ++it) {
    int idx = it * 256 + t;
    int r = idx >> 6, c = idx & 63;                    // r -> n, c -> k (coalesced)
    out[(size_t)(n0 + r) * K + k0 + c] = tile[r][c];
  }
}

// ---------------------------------------------------------------------------
// LayerNorm (fp32 in) -> bf16 out. One wave per 512-el row.
// ---------------------------------------------------------------------------
__global__ void ln_kernel(const float* __restrict__ x, const float* __restrict__ sc,
                          const float* __restrict__ bi, bf16* __restrict__ out) {
  int wv = threadIdx.x >> 6;
  int lane = threadIdx.x & 63;
  int row = blockIdx.x * 4 + wv;
  const float* xr = x + (size_t)row * DDIM + lane * 8;
  float4 v0 = *(const float4*)(xr);
  float4 v1 = *(const float4*)(xr + 4);
  float vv[8] = {v0.x, v0.y, v0.z, v0.w, v1.x, v1.y, v1.z, v1.w};
  float s = 0.f;
  for (int i = 0; i < 8; ++i) s += vv[i];
  for (int m = 1; m < 64; m <<= 1) s += __shfl_xor(s, m, 64);
  float mean = s * (1.0f / DDIM);
  float vs = 0.f;
  for (int i = 0; i < 8; ++i) { float d = vv[i] - mean; vs += d * d; }
  for (int m = 1; m < 64; m <<= 1) vs += __shfl_xor(vs, m, 64);
  float rstd = rsqrtf(vs * (1.0f / DDIM) + 1e-6f);
  __align__(16) bf16 ov[8];
  int c0 = lane * 8;
  for (int i = 0; i < 8; ++i) {
    float y = (vv[i] - mean) * rstd * sc[c0 + i] + bi[c0 + i];
    ov[i] = __float2bfloat16(y);
  }
  *(uint4*)(&out[(size_t)row * DDIM + c0]) = *(const uint4*)ov;
}

// ---------------------------------------------------------------------------
// GEMM: C[M][N] = A[M][K] (bf16 row-major) x BT[N][K] (bf16), epilogue by EPI.
// EPI 0: scatter q/k to [B,H,S,64], v TRANSPOSED to [B,H,64,S]  (out0 = qkv)
// EPI 1: += ep_add (fp32), write fp32          (out-proj + residual)
// EPI 2: += ep_bias, gelu, write bf16          (MLP up)
// EPI 3: += ep_bias + ep_add, write fp32       (MLP down + residual -> d_out)
// ---------------------------------------------------------------------------
template <int EPI>
__global__ __launch_bounds__(256, 2)
void gemm_kernel(const bf16* __restrict__ A, const bf16* __restrict__ BT,
                 int M, int N, int K,
                 const float* __restrict__ ep_add, const float* __restrict__ ep_bias,
                 void* __restrict__ out0) {
  __shared__ __align__(16) bf16 As[128][40];
  __shared__ __align__(16) bf16 Bs[128][40];
  int t = threadIdx.x;
  int wv = t >> 6, lane = t & 63;
  int wr = wv >> 1, wc = wv & 1;
  int g = lane >> 4, lr = lane & 15;
  int m0 = blockIdx.y * 128, n0 = blockIdx.x * 128;
  f32x4 acc[4][4] = {};
  for (int k0 = 0; k0 < K; k0 += 32) {
    __syncthreads();
    for (int s = 0; s < 2; ++s) {
      int c = t + s * 256;
      int row = c >> 2, k8 = (c & 3) * 8;
      *(uint4*)&As[row][k8] = *(const uint4*)&A[(size_t)(m0 + row) * K + k0 + k8];
      *(uint4*)&Bs[row][k8] = *(const uint4*)&BT[(size_t)(n0 + row) * K + k0 + k8];
    }
    __syncthreads();
    bf16x8 af[4], bfr[4];
    for (int i = 0; i < 4; ++i) af[i] = *(const bf16x8*)&As[wr * 64 + i * 16 + lr][g * 8];
    for (int j = 0; j < 4; ++j) bfr[j] = *(const bf16x8*)&Bs[wc * 64 + j * 16 + lr][g * 8];
    for (int i = 0; i < 4; ++i)
      for (int j = 0; j < 4; ++j)
        acc[i][j] = __builtin_amdgcn_mfma_f32_16x16x32_bf16(af[i], bfr[j], acc[i][j], 0, 0, 0);
  }
  for (int i = 0; i < 4; ++i)
    for (int j = 0; j < 4; ++j)
      for (int r = 0; r < 4; ++r) {
        int m = m0 + wr * 64 + i * 16 + g * 4 + r;
        int n = n0 + wc * 64 + j * 16 + lr;
        float val = acc[i][j][r];
        if constexpr (EPI == 0) {
          bf16* qkv = (bf16*)out0;
          int which = n >> 9;
          int hh = (n >> 6) & 7;
          int hd = n & 63;
          int b = m >> 11, sTok = m & 2047;
          size_t off;
          if (which == 2) {
            // V transposed: [B,H,64,S]
            off = (size_t)2 * (BB * NHEAD * SS * HDIM) +
                  ((size_t)(b * NHEAD + hh) * HDIM + hd) * SS + sTok;
          } else {
            off = (size_t)which * (BB * NHEAD * SS * HDIM) +
                  ((size_t)(b * NHEAD + hh) * SS + sTok) * HDIM + hd;
          }
          qkv[off] = __float2bfloat16(val);
        } else if constexpr (EPI == 1) {
          ((float*)out0)[(size_t)m * N + n] = val + ep_add[(size_t)m * N + n];
        } else if constexpr (EPI == 2) {
          float xb = val + ep_bias[n];
          float inner = 0.7978845608028654f * (xb + 0.044715f * xb * xb * xb);
          float ge = 0.5f * xb * (1.0f + tanhf(inner));
          ((bf16*)out0)[(size_t)m * N + n] = __float2bfloat16(ge);
        } else {
          ((float*)out0)[(size_t)m * N + n] = val + ep_bias[n] + ep_add[(size_t)m * N + n];
        }
      }
}

// ---------------------------------------------------------------------------
// Block-sparse flash attention v2. One wave per 16 q-rows.
// Grid: B*H*(S/16) blocks of 64 threads. No __syncthreads anywhere.
// Q,K: [B*H][S][64] bf16. VT: [B*H][64][S] bf16. ctx out: [NTOK][512] bf16.
// mask(i,j) = (|i-j|<=256) || i<64 || j<64
// ---------------------------------------------------------------------------
template <bool MASK>
__device__ __forceinline__ void attn_tile(
    int kb, int qq0, int g, int lr,
    const bf16* __restrict__ Kh, const bf16* __restrict__ VTh,
    const bf16x8& aq0, const bf16x8& aq1,
    float* mrun, float* lsum, f32x4* accO, bf16 (*Plds)[40]) {
  bf16x8 kf0a = *(const bf16x8*)&Kh[(size_t)(kb + lr) * HDIM + g * 8];
  bf16x8 kf0b = *(const bf16x8*)&Kh[(size_t)(kb + lr) * HDIM + 32 + g * 8];
  bf16x8 kf1a = *(const bf16x8*)&Kh[(size_t)(kb + 16 + lr) * HDIM + g * 8];
  bf16x8 kf1b = *(const bf16x8*)&Kh[(size_t)(kb + 16 + lr) * HDIM + 32 + g * 8];
  f32x4 s0 = {}, s1 = {};
  s0 = __builtin_amdgcn_mfma_f32_16x16x32_bf16(aq0, kf0a, s0, 0, 0, 0);
  s0 = __builtin_amdgcn_mfma_f32_16x16x32_bf16(aq1, kf0b, s0, 0, 0, 0);
  s1 = __builtin_amdgcn_mfma_f32_16x16x32_bf16(aq0, kf1a, s1, 0, 0, 0);
  s1 = __builtin_amdgcn_mfma_f32_16x16x32_bf16(aq1, kf1b, s1, 0, 0, 0);
  float p0[4], p1[4], tmax[4];
  for (int r = 0; r < 4; ++r) {
    if constexpr (MASK) {
      int i = qq0 + g * 4 + r;
      int d0 = i - (kb + lr), d1 = i - (kb + 16 + lr);
      bool ok0 = (unsigned)(d0 + WHALF) <= 2u * WHALF;
      bool ok1 = (unsigned)(d1 + WHALF) <= 2u * WHALF;
      p0[r] = ok0 ? s0[r] : NEGBIG;
      p1[r] = ok1 ? s1[r] : NEGBIG;
    } else {
      p0[r] = s0[r];
      p1[r] = s1[r];
    }
    tmax[r] = fmaxf(p0[r], p1[r]);
  }
  for (int m = 1; m < 16; m <<= 1)
    for (int r = 0; r < 4; ++r) tmax[r] = fmaxf(tmax[r], __shfl_xor(tmax[r], m, 64));
  float rowsum[4];
  for (int r = 0; r < 4; ++r) {
    float mnew = fmaxf(mrun[r], tmax[r]);
    float resc = __expf(mrun[r] - mnew);
    mrun[r] = mnew;
    lsum[r] *= resc;
    for (int dc = 0; dc < 4; ++dc) accO[dc][r] *= resc;
    p0[r] = __expf(p0[r] - mnew);
    p1[r] = __expf(p1[r] - mnew);
    rowsum[r] = p0[r] + p1[r];
  }
  for (int m = 1; m < 16; m <<= 1)
    for (int r = 0; r < 4; ++r) rowsum[r] += __shfl_xor(rowsum[r], m, 64);
  for (int r = 0; r < 4; ++r) lsum[r] += rowsum[r];
  for (int r = 0; r < 4; ++r) {
    Plds[g * 4 + r][lr] = __float2bfloat16(p0[r]);
    Plds[g * 4 + r][16 + lr] = __float2bfloat16(p1[r]);
  }
  asm volatile("s_waitcnt lgkmcnt(0)" ::: "memory");
  bf16x8 pa = *(const bf16x8*)&Plds[lr][g * 8];
  for (int dc = 0; dc < 4; ++dc) {
    bf16x8 vf = *(const bf16x8*)&VTh[(size_t)(dc * 16 + lr) * SS + kb + g * 8];
    accO[dc] = __builtin_amdgcn_mfma_f32_16x16x32_bf16(pa, vf, accO[dc], 0, 0, 0);
  }
}

__global__ __launch_bounds__(64, 4)
void attn_kernel(const bf16* __restrict__ Qb, const bf16* __restrict__ Kb,
                 const bf16* __restrict__ VTb, bf16* __restrict__ ctx) {
  __shared__ __align__(16) bf16 Plds[16][40];
  int lane = threadIdx.x;
  int g = lane >> 4, lr = lane & 15;
  int bh = blockIdx.x >> 7;
  int qq0 = (blockIdx.x & 127) * 16;
  int b = bh >> 3, h = bh & 7;
  const bf16* Qh = Qb + (size_t)bh * SS * HDIM;
  const bf16* Kh = Kb + (size_t)bh * SS * HDIM;
  const bf16* VTh = VTb + (size_t)bh * HDIM * SS;
  int qrow = qq0 + lr;
  bf16x8 aq0 = *(const bf16x8*)&Qh[(size_t)qrow * HDIM + g * 8];
  bf16x8 aq1 = *(const bf16x8*)&Qh[(size_t)qrow * HDIM + 32 + g * 8];
  float mrun[4], lsum[4];
  f32x4 accO[4] = {};
  for (int r = 0; r < 4; ++r) { mrun[r] = -3e38f; lsum[r] = 0.f; }
  if (qq0 < NGLOB) {
    // global q-rows: attend everywhere, no masking
    for (int kb = 0; kb < SS; kb += 32)
      attn_tile<false>(kb, qq0, g, lr, Kh, VTh, aq0, aq1, mrun, lsum, accO, Plds);
  } else {
    // global columns first (guarantees real max before any masked tile)
    attn_tile<false>(0, qq0, g, lr, Kh, VTh, aq0, aq1, mrun, lsum, accO, Plds);
    attn_tile<false>(32, qq0, g, lr, Kh, VTh, aq0, aq1, mrun, lsum, accO, Plds);
    int blo = qq0 - WHALF;
    int bs = (blo < NGLOB) ? NGLOB : (blo & ~31);
    int bhi = qq0 + 15 + WHALF;
    int be = (bhi + 1 < SS) ? (bhi + 1) : SS;
    for (int kb = bs; kb < be; kb += 32)
      attn_tile<true>(kb, qq0, g, lr, Kh, VTh, aq0, aq1, mrun, lsum, accO, Plds);
  }
  for (int dc = 0; dc < 4; ++dc)
    for (int r = 0; r < 4; ++r) {
      int m = b * SS + qq0 + g * 4 + r;
      int col = h * HDIM + dc * 16 + lr;
      float val = accO[dc][r] / lsum[r];
      ctx[(size_t)m * DDIM + col] = __float2bfloat16(val);
    }
}

// ---------------------------------------------------------------------------
extern "C" void kernel_launch(void* const* d_in, const int* in_sizes, int n_in,
                              void* d_out, int out_size, void* d_ws, size_t ws_size,
                              hipStream_t stream) {
  const float* inputs = (const float*)d_in[0];
  // d_in[1] = global_mask (deterministic: first 64 tokens) -- hardcoded
  const float* ln1_s = (const float*)d_in[2];
  const float* ln1_b = (const float*)d_in[3];
  const float* wq = (const float*)d_in[4];
  const float* wk = (const float*)d_in[5];
  const float* wv = (const float*)d_in[6];
  const float* wo = (const float*)d_in[7];
  const float* ln2_s = (const float*)d_in[8];
  const float* ln2_b = (const float*)d_in[9];
  const float* w1 = (const float*)d_in[10];
  const float* b1 = (const float*)d_in[11];
  const float* w2 = (const float*)d_in[12];
  const float* b2 = (const float*)d_in[13];

  char* ws = (char*)d_ws;
  bf16* x1    = (bf16*)(ws + OFF_X1);
  bf16* wqkvT = (bf16*)(ws + OFF_WQKVT);
  bf16* woT   = (bf16*)(ws + OFF_WOT);
  bf16* w1T   = (bf16*)(ws + OFF_W1T);
  bf16* w2T   = (bf16*)(ws + OFF_W2T);
  bf16* qkv   = (bf16*)(ws + OFF_QKV);
  bf16* ctx   = (bf16*)(ws + OFF_CTX);
  float* xres = (float*)(ws + OFF_XRES);
  bf16* y1    = (bf16*)(ws + OFF_Y1);
  bf16* h1    = (bf16*)(ws + OFF_H1);
  size_t headsz = (size_t)BB * NHEAD * SS * HDIM;  // elements per q/k/v

  // Weight prep (fold 1/sqrt(64) into wq)
  transpose_cast_kernel<<<dim3(8, 8), 256, 0, stream>>>(wq, wqkvT, 512, 512, 0.125f);
  transpose_cast_kernel<<<dim3(8, 8), 256, 0, stream>>>(wk, wqkvT + (size_t)512 * 512, 512, 512, 1.f);
  transpose_cast_kernel<<<dim3(8, 8), 256, 0, stream>>>(wv, wqkvT + (size_t)1024 * 512, 512, 512, 1.f);
  transpose_cast_kernel<<<dim3(8, 8), 256, 0, stream>>>(wo, woT, 512, 512, 1.f);
  transpose_cast_kernel<<<dim3(32, 8), 256, 0, stream>>>(w1, w1T, 512, 2048, 1.f);
  transpose_cast_kernel<<<dim3(8, 32), 256, 0, stream>>>(w2, w2T, 2048, 512, 1.f);

  // LN1
  ln_kernel<<<NTOK / 4, 256, 0, stream>>>(inputs, ln1_s, ln1_b, x1);
  // QKV projection (V written transposed)
  gemm_kernel<0><<<dim3(12, 32), 256, 0, stream>>>(x1, wqkvT, NTOK, 1536, 512, nullptr, nullptr, qkv);
  // Attention
  attn_kernel<<<BB * NHEAD * (SS / 16), 64, 0, stream>>>(qkv, qkv + headsz, qkv + 2 * headsz, ctx);
  // Output projection + residual
  gemm_kernel<1><<<dim3(4, 32), 256, 0, stream>>>(ctx, woT, NTOK, 512, 512, inputs, nullptr, xres);
  // LN2
  ln_kernel<<<NTOK / 4, 256, 0, stream>>>(xres, ln2_s, ln2_b, y1);
  // MLP
  gemm_kernel<2><<<dim3(16, 32), 256, 0, stream>>>(y1, w1T, NTOK, 2048, 512, nullptr, b1, h1);
  gemm_kernel<3><<<dim3(4, 32), 256, 0, stream>>>(h1, w2T, NTOK, 512, 2048, xres, b2, (float*)d_out);
}

// Round 3
// 184.596 us; speedup vs baseline: 1.3743x; 1.3743x over previous
//
#include <hip/hip_runtime.h>
#include <hip/hip_bf16.h>

typedef __attribute__((ext_vector_type(4))) float f32x4;
typedef __bf16 bf16x8 __attribute__((ext_vector_type(8)));
using bf16 = __hip_bfloat16;

// Problem constants
constexpr int BB = 2, SS = 2048, DDIM = 512, NHEAD = 8, HDIM = 64, MLPD = 2048;
constexpr int NTOK = BB * SS;          // 4096
constexpr int WHALF = 256;             // window // 2
constexpr int NGLOB = 64;
constexpr float NEGBIG = -1e10f;

// Workspace layout (bytes)
constexpr size_t SZ_X1    = (size_t)NTOK * DDIM * 2;
constexpr size_t SZ_WQKVT = (size_t)1536 * DDIM * 2;
constexpr size_t SZ_WOT   = (size_t)DDIM * DDIM * 2;
constexpr size_t SZ_W1T   = (size_t)MLPD * DDIM * 2;
constexpr size_t SZ_W2T   = (size_t)DDIM * MLPD * 2;
constexpr size_t SZ_HEAD  = (size_t)BB * NHEAD * SS * HDIM * 2;  // one of q/k/v
constexpr size_t SZ_QKV   = 3 * SZ_HEAD;
constexpr size_t SZ_CTX   = (size_t)NTOK * DDIM * 2;
constexpr size_t SZ_XRES  = (size_t)NTOK * DDIM * 4;
constexpr size_t SZ_Y1    = (size_t)NTOK * DDIM * 2;
constexpr size_t SZ_H1    = (size_t)NTOK * MLPD * 2;

constexpr size_t OFF_X1    = 0;
constexpr size_t OFF_WQKVT = OFF_X1 + SZ_X1;
constexpr size_t OFF_WOT   = OFF_WQKVT + SZ_WQKVT;
constexpr size_t OFF_W1T   = OFF_WOT + SZ_WOT;
constexpr size_t OFF_W2T   = OFF_W1T + SZ_W1T;
constexpr size_t OFF_QKV   = OFF_W2T + SZ_W2T;
constexpr size_t OFF_CTX   = OFF_QKV + SZ_QKV;
constexpr size_t OFF_XRES  = OFF_CTX + SZ_CTX;
constexpr size_t OFF_Y1    = OFF_XRES + SZ_XRES;
constexpr size_t OFF_H1    = OFF_Y1 + SZ_Y1;
// global-attention split partials: 64 groups (bh*4+qt) x 4 splits
constexpr size_t OFF_GACC  = OFF_H1 + SZ_H1;                  // [256][16][64] f32
constexpr size_t OFF_GM    = OFF_GACC + (size_t)256 * 16 * 64 * 4;  // [256][16] f32
constexpr size_t OFF_GL    = OFF_GM + (size_t)256 * 16 * 4;         // [256][16] f32

// ---------------------------------------------------------------------------
// Transpose + cast fp32 [K][N] -> bf16 [N][K], with scale.
// ---------------------------------------------------------------------------
__global__ void transpose_cast_kernel(const float* __restrict__ in, bf16* __restrict__ out,
                                      int K, int N, float scale) {
  __shared__ __align__(16) bf16 tile[64][65];
  int k0 = blockIdx.y * 64;
  int n0 = blockIdx.x * 64;
  int t = threadIdx.x;
  for (int it = 0; it < 16; ++it) {
    int idx = it * 256 + t;
    int r = idx >> 6, c = idx & 63;
    float v = in[(size_t)(k0 + r) * N + n0 + c] * scale;
    tile[c][r] = __float2bfloat16(v);
  }
  __syncthreads();
  for (int it = 0; it < 16; ++it) {
    int idx = it * 256 + t;
    int r = idx >> 6, c = idx & 63;
    out[(size_t)(n0 + r) * K + k0 + c] = tile[r][c];
  }
}

// ---------------------------------------------------------------------------
// LayerNorm (fp32 in) -> bf16 out. One wave per 512-el row.
// ---------------------------------------------------------------------------
__global__ void ln_kernel(const float* __restrict__ x, const float* __restrict__ sc,
                          const float* __restrict__ bi, bf16* __restrict__ out) {
  int wv = threadIdx.x >> 6;
  int lane = threadIdx.x & 63;
  int row = blockIdx.x * 4 + wv;
  const float* xr = x + (size_t)row * DDIM + lane * 8;
  float4 v0 = *(const float4*)(xr);
  float4 v1 = *(const float4*)(xr + 4);
  float vv[8] = {v0.x, v0.y, v0.z, v0.w, v1.x, v1.y, v1.z, v1.w};
  float s = 0.f;
  for (int i = 0; i < 8; ++i) s += vv[i];
  for (int m = 1; m < 64; m <<= 1) s += __shfl_xor(s, m, 64);
  float mean = s * (1.0f / DDIM);
  float vs = 0.f;
  for (int i = 0; i < 8; ++i) { float d = vv[i] - mean; vs += d * d; }
  for (int m = 1; m < 64; m <<= 1) vs += __shfl_xor(vs, m, 64);
  float rstd = rsqrtf(vs * (1.0f / DDIM) + 1e-6f);
  __align__(16) bf16 ov[8];
  int c0 = lane * 8;
  for (int i = 0; i < 8; ++i) {
    float y = (vv[i] - mean) * rstd * sc[c0 + i] + bi[c0 + i];
    ov[i] = __float2bfloat16(y);
  }
  *(uint4*)(&out[(size_t)row * DDIM + c0]) = *(const uint4*)ov;
}

// ---------------------------------------------------------------------------
// GEMM: C[M][N] = A[M][K] (bf16 row-major) x BT[N][K] (bf16), epilogue by EPI.
// ---------------------------------------------------------------------------
template <int EPI>
__global__ __launch_bounds__(256, 2)
void gemm_kernel(const bf16* __restrict__ A, const bf16* __restrict__ BT,
                 int M, int N, int K,
                 const float* __restrict__ ep_add, const float* __restrict__ ep_bias,
                 void* __restrict__ out0) {
  __shared__ __align__(16) bf16 As[128][40];
  __shared__ __align__(16) bf16 Bs[128][40];
  int t = threadIdx.x;
  int wv = t >> 6, lane = t & 63;
  int wr = wv >> 1, wc = wv & 1;
  int g = lane >> 4, lr = lane & 15;
  int m0 = blockIdx.y * 128, n0 = blockIdx.x * 128;
  f32x4 acc[4][4] = {};
  for (int k0 = 0; k0 < K; k0 += 32) {
    __syncthreads();
    for (int s = 0; s < 2; ++s) {
      int c = t + s * 256;
      int row = c >> 2, k8 = (c & 3) * 8;
      *(uint4*)&As[row][k8] = *(const uint4*)&A[(size_t)(m0 + row) * K + k0 + k8];
      *(uint4*)&Bs[row][k8] = *(const uint4*)&BT[(size_t)(n0 + row) * K + k0 + k8];
    }
    __syncthreads();
    bf16x8 af[4], bfr[4];
    for (int i = 0; i < 4; ++i) af[i] = *(const bf16x8*)&As[wr * 64 + i * 16 + lr][g * 8];
    for (int j = 0; j < 4; ++j) bfr[j] = *(const bf16x8*)&Bs[wc * 64 + j * 16 + lr][g * 8];
    for (int i = 0; i < 4; ++i)
      for (int j = 0; j < 4; ++j)
        acc[i][j] = __builtin_amdgcn_mfma_f32_16x16x32_bf16(af[i], bfr[j], acc[i][j], 0, 0, 0);
  }
  for (int i = 0; i < 4; ++i)
    for (int j = 0; j < 4; ++j)
      for (int r = 0; r < 4; ++r) {
        int m = m0 + wr * 64 + i * 16 + g * 4 + r;
        int n = n0 + wc * 64 + j * 16 + lr;
        float val = acc[i][j][r];
        if constexpr (EPI == 0) {
          bf16* qkv = (bf16*)out0;
          int which = n >> 9;
          int hh = (n >> 6) & 7;
          int hd = n & 63;
          int b = m >> 11, sTok = m & 2047;
          size_t off;
          if (which == 2) {
            off = (size_t)2 * (BB * NHEAD * SS * HDIM) +
                  ((size_t)(b * NHEAD + hh) * HDIM + hd) * SS + sTok;
          } else {
            off = (size_t)which * (BB * NHEAD * SS * HDIM) +
                  ((size_t)(b * NHEAD + hh) * SS + sTok) * HDIM + hd;
          }
          qkv[off] = __float2bfloat16(val);
        } else if constexpr (EPI == 1) {
          ((float*)out0)[(size_t)m * N + n] = val + ep_add[(size_t)m * N + n];
        } else if constexpr (EPI == 2) {
          float xb = val + ep_bias[n];
          float inner = 0.7978845608028654f * (xb + 0.044715f * xb * xb * xb);
          float ge = 0.5f * xb * (1.0f + tanhf(inner));
          ((bf16*)out0)[(size_t)m * N + n] = __float2bfloat16(ge);
        } else {
          ((float*)out0)[(size_t)m * N + n] = val + ep_bias[n] + ep_add[(size_t)m * N + n];
        }
      }
}

// ---------------------------------------------------------------------------
// Block-sparse flash attention v3. One wave / 16 q-rows. V loads hoisted.
// Unified grid (XCD-swizzled): 1984 band blocks + 256 global-split blocks.
// ---------------------------------------------------------------------------
template <bool MASK>
__device__ __forceinline__ void attn_tile(
    int kb, int qq0, int g, int lr,
    const bf16* __restrict__ Kh, const bf16* __restrict__ VTh,
    const bf16x8& aq0, const bf16x8& aq1,
    float* mrun, float* lsum, f32x4* accO, bf16 (*Plds)[40]) {
  // K loads
  bf16x8 kf0a = *(const bf16x8*)&Kh[(size_t)(kb + lr) * HDIM + g * 8];
  bf16x8 kf0b = *(const bf16x8*)&Kh[(size_t)(kb + lr) * HDIM + 32 + g * 8];
  bf16x8 kf1a = *(const bf16x8*)&Kh[(size_t)(kb + 16 + lr) * HDIM + g * 8];
  bf16x8 kf1b = *(const bf16x8*)&Kh[(size_t)(kb + 16 + lr) * HDIM + 32 + g * 8];
  // V loads hoisted (independent of softmax) -- overlap latency with QK+softmax
  bf16x8 vf0 = *(const bf16x8*)&VTh[(size_t)(0 * 16 + lr) * SS + kb + g * 8];
  bf16x8 vf1 = *(const bf16x8*)&VTh[(size_t)(1 * 16 + lr) * SS + kb + g * 8];
  bf16x8 vf2 = *(const bf16x8*)&VTh[(size_t)(2 * 16 + lr) * SS + kb + g * 8];
  bf16x8 vf3 = *(const bf16x8*)&VTh[(size_t)(3 * 16 + lr) * SS + kb + g * 8];
  f32x4 s0 = {}, s1 = {};
  s0 = __builtin_amdgcn_mfma_f32_16x16x32_bf16(aq0, kf0a, s0, 0, 0, 0);
  s0 = __builtin_amdgcn_mfma_f32_16x16x32_bf16(aq1, kf0b, s0, 0, 0, 0);
  s1 = __builtin_amdgcn_mfma_f32_16x16x32_bf16(aq0, kf1a, s1, 0, 0, 0);
  s1 = __builtin_amdgcn_mfma_f32_16x16x32_bf16(aq1, kf1b, s1, 0, 0, 0);
  float p0[4], p1[4], tmax[4];
  for (int r = 0; r < 4; ++r) {
    if constexpr (MASK) {
      int i = qq0 + g * 4 + r;
      int d0 = i - (kb + lr), d1 = i - (kb + 16 + lr);
      bool ok0 = (unsigned)(d0 + WHALF) <= 2u * WHALF;
      bool ok1 = (unsigned)(d1 + WHALF) <= 2u * WHALF;
      p0[r] = ok0 ? s0[r] : NEGBIG;
      p1[r] = ok1 ? s1[r] : NEGBIG;
    } else {
      p0[r] = s0[r];
      p1[r] = s1[r];
    }
    tmax[r] = fmaxf(p0[r], p1[r]);
  }
  for (int m = 1; m < 16; m <<= 1)
    for (int r = 0; r < 4; ++r) tmax[r] = fmaxf(tmax[r], __shfl_xor(tmax[r], m, 64));
  float rowsum[4];
  for (int r = 0; r < 4; ++r) {
    float mnew = fmaxf(mrun[r], tmax[r]);
    float resc = __expf(mrun[r] - mnew);
    mrun[r] = mnew;
    lsum[r] *= resc;
    for (int dc = 0; dc < 4; ++dc) accO[dc][r] *= resc;
    p0[r] = __expf(p0[r] - mnew);
    p1[r] = __expf(p1[r] - mnew);
    rowsum[r] = p0[r] + p1[r];
  }
  for (int m = 1; m < 16; m <<= 1)
    for (int r = 0; r < 4; ++r) rowsum[r] += __shfl_xor(rowsum[r], m, 64);
  for (int r = 0; r < 4; ++r) lsum[r] += rowsum[r];
  for (int r = 0; r < 4; ++r) {
    Plds[g * 4 + r][lr] = __float2bfloat16(p0[r]);
    Plds[g * 4 + r][16 + lr] = __float2bfloat16(p1[r]);
  }
  asm volatile("s_waitcnt lgkmcnt(0)" ::: "memory");
  bf16x8 pa = *(const bf16x8*)&Plds[lr][g * 8];
  accO[0] = __builtin_amdgcn_mfma_f32_16x16x32_bf16(pa, vf0, accO[0], 0, 0, 0);
  accO[1] = __builtin_amdgcn_mfma_f32_16x16x32_bf16(pa, vf1, accO[1], 0, 0, 0);
  accO[2] = __builtin_amdgcn_mfma_f32_16x16x32_bf16(pa, vf2, accO[2], 0, 0, 0);
  accO[3] = __builtin_amdgcn_mfma_f32_16x16x32_bf16(pa, vf3, accO[3], 0, 0, 0);
}

constexpr int NBAND = 16 * 124;   // 1984
constexpr int NGSPL = 16 * 4 * 4; // 256
constexpr int NWG   = NBAND + NGSPL; // 2240 (divisible by 8)

__global__ __launch_bounds__(64, 4)
void attn_kernel(const bf16* __restrict__ Qb, const bf16* __restrict__ Kb,
                 const bf16* __restrict__ VTb, bf16* __restrict__ ctx,
                 float* __restrict__ gacc, float* __restrict__ gm,
                 float* __restrict__ gl) {
  __shared__ __align__(16) bf16 Plds[16][40];
  int lane = threadIdx.x;
  int g = lane >> 4, lr = lane & 15;
  int bid = blockIdx.x;
  int swz = (bid & 7) * (NWG / 8) + (bid >> 3);   // XCD-contiguous chunks
  float mrun[4], lsum[4];
  f32x4 accO[4] = {};
  for (int r = 0; r < 4; ++r) { mrun[r] = -3e38f; lsum[r] = 0.f; }
  if (swz < NBAND) {
    int bh = swz / 124;
    int qq0 = ((swz % 124) + 4) * 16;   // 64..2032
    int b = bh >> 3, h = bh & 7;
    const bf16* Qh = Qb + (size_t)bh * SS * HDIM;
    const bf16* Kh = Kb + (size_t)bh * SS * HDIM;
    const bf16* VTh = VTb + (size_t)bh * HDIM * SS;
    int qrow = qq0 + lr;
    bf16x8 aq0 = *(const bf16x8*)&Qh[(size_t)qrow * HDIM + g * 8];
    bf16x8 aq1 = *(const bf16x8*)&Qh[(size_t)qrow * HDIM + 32 + g * 8];
    // global columns first (real max before masked tiles)
    attn_tile<false>(0, qq0, g, lr, Kh, VTh, aq0, aq1, mrun, lsum, accO, Plds);
    attn_tile<false>(32, qq0, g, lr, Kh, VTh, aq0, aq1, mrun, lsum, accO, Plds);
    int blo = qq0 - WHALF;
    int bs = (blo < NGLOB) ? NGLOB : (blo & ~31);
    int bhi = qq0 + 15 + WHALF;
    int be = (bhi + 1 < SS) ? (bhi + 1) : SS;
    for (int kb = bs; kb < be; kb += 32)
      attn_tile<true>(kb, qq0, g, lr, Kh, VTh, aq0, aq1, mrun, lsum, accO, Plds);
    for (int dc = 0; dc < 4; ++dc)
      for (int r = 0; r < 4; ++r) {
        int m = b * SS + qq0 + g * 4 + r;
        int col = h * HDIM + dc * 16 + lr;
        ctx[(size_t)m * DDIM + col] = __float2bfloat16(accO[dc][r] / lsum[r]);
      }
  } else {
    int gidx = swz - NBAND;
    int bh = gidx >> 4, qt = (gidx >> 2) & 3, sp = gidx & 3;
    int qq0 = qt * 16;                  // <64: global rows, no masking
    const bf16* Qh = Qb + (size_t)bh * SS * HDIM;
    const bf16* Kh = Kb + (size_t)bh * SS * HDIM;
    const bf16* VTh = VTb + (size_t)bh * HDIM * SS;
    int qrow = qq0 + lr;
    bf16x8 aq0 = *(const bf16x8*)&Qh[(size_t)qrow * HDIM + g * 8];
    bf16x8 aq1 = *(const bf16x8*)&Qh[(size_t)qrow * HDIM + 32 + g * 8];
    int k0 = sp * (SS / 4);
    for (int kb = k0; kb < k0 + SS / 4; kb += 32)
      attn_tile<false>(kb, qq0, g, lr, Kh, VTh, aq0, aq1, mrun, lsum, accO, Plds);
    int grp = (bh * 4 + qt) * 4 + sp;
    for (int dc = 0; dc < 4; ++dc)
      for (int r = 0; r < 4; ++r)
        gacc[((size_t)grp * 16 + g * 4 + r) * 64 + dc * 16 + lr] = accO[dc][r];
    if (lr == 0)
      for (int r = 0; r < 4; ++r) {
        gm[grp * 16 + g * 4 + r] = mrun[r];
        gl[grp * 16 + g * 4 + r] = lsum[r];
      }
  }
}

// Merge the 4 KV-splits of each global q-tile.
__global__ __launch_bounds__(64, 4)
void attn_combine_kernel(const float* __restrict__ gacc, const float* __restrict__ gm,
                         const float* __restrict__ gl, bf16* __restrict__ ctx) {
  int grp4 = blockIdx.x;          // bh*4 + qt, 0..63
  int bh = grp4 >> 2, qt = grp4 & 3;
  int b = bh >> 3, h = bh & 7;
  int c = threadIdx.x;            // 0..63
  for (int r = 0; r < 16; ++r) {
    float ms[4], M = -3e38f;
    for (int s2 = 0; s2 < 4; ++s2) {
      ms[s2] = gm[(grp4 * 4 + s2) * 16 + r];
      M = fmaxf(M, ms[s2]);
    }
    float L = 0.f, val = 0.f;
    for (int s2 = 0; s2 < 4; ++s2) {
      float w = __expf(ms[s2] - M);
      L += gl[(grp4 * 4 + s2) * 16 + r] * w;
      val += gacc[((size_t)(grp4 * 4 + s2) * 16 + r) * 64 + c] * w;
    }
    ctx[(size_t)(b * SS + qt * 16 + r) * DDIM + h * HDIM + c] = __float2bfloat16(val / L);
  }
}

// ---------------------------------------------------------------------------
extern "C" void kernel_launch(void* const* d_in, const int* in_sizes, int n_in,
                              void* d_out, int out_size, void* d_ws, size_t ws_size,
                              hipStream_t stream) {
  const float* inputs = (const float*)d_in[0];
  const float* ln1_s = (const float*)d_in[2];
  const float* ln1_b = (const float*)d_in[3];
  const float* wq = (const float*)d_in[4];
  const float* wk = (const float*)d_in[5];
  const float* wv = (const float*)d_in[6];
  const float* wo = (const float*)d_in[7];
  const float* ln2_s = (const float*)d_in[8];
  const float* ln2_b = (const float*)d_in[9];
  const float* w1 = (const float*)d_in[10];
  const float* b1 = (const float*)d_in[11];
  const float* w2 = (const float*)d_in[12];
  const float* b2 = (const float*)d_in[13];

  char* ws = (char*)d_ws;
  bf16* x1    = (bf16*)(ws + OFF_X1);
  bf16* wqkvT = (bf16*)(ws + OFF_WQKVT);
  bf16* woT   = (bf16*)(ws + OFF_WOT);
  bf16* w1T   = (bf16*)(ws + OFF_W1T);
  bf16* w2T   = (bf16*)(ws + OFF_W2T);
  bf16* qkv   = (bf16*)(ws + OFF_QKV);
  bf16* ctx   = (bf16*)(ws + OFF_CTX);
  float* xres = (float*)(ws + OFF_XRES);
  bf16* y1    = (bf16*)(ws + OFF_Y1);
  bf16* h1    = (bf16*)(ws + OFF_H1);
  float* gacc = (float*)(ws + OFF_GACC);
  float* gm   = (float*)(ws + OFF_GM);
  float* gl   = (float*)(ws + OFF_GL);
  size_t headsz = (size_t)BB * NHEAD * SS * HDIM;

  // Weight prep (fold 1/sqrt(64) into wq)
  transpose_cast_kernel<<<dim3(8, 8), 256, 0, stream>>>(wq, wqkvT, 512, 512, 0.125f);
  transpose_cast_kernel<<<dim3(8, 8), 256, 0, stream>>>(wk, wqkvT + (size_t)512 * 512, 512, 512, 1.f);
  transpose_cast_kernel<<<dim3(8, 8), 256, 0, stream>>>(wv, wqkvT + (size_t)1024 * 512, 512, 512, 1.f);
  transpose_cast_kernel<<<dim3(8, 8), 256, 0, stream>>>(wo, woT, 512, 512, 1.f);
  transpose_cast_kernel<<<dim3(32, 8), 256, 0, stream>>>(w1, w1T, 512, 2048, 1.f);
  transpose_cast_kernel<<<dim3(8, 32), 256, 0, stream>>>(w2, w2T, 2048, 512, 1.f);

  // LN1
  ln_kernel<<<NTOK / 4, 256, 0, stream>>>(inputs, ln1_s, ln1_b, x1);
  // QKV projection (V written transposed)
  gemm_kernel<0><<<dim3(12, 32), 256, 0, stream>>>(x1, wqkvT, NTOK, 1536, 512, nullptr, nullptr, qkv);
  // Attention (band + global-split), then combine
  attn_kernel<<<NWG, 64, 0, stream>>>(qkv, qkv + headsz, qkv + 2 * headsz, ctx, gacc, gm, gl);
  attn_combine_kernel<<<64, 64, 0, stream>>>(gacc, gm, gl, ctx);
  // Output projection + residual
  gemm_kernel<1><<<dim3(4, 32), 256, 0, stream>>>(ctx, woT, NTOK, 512, 512, inputs, nullptr, xres);
  // LN2
  ln_kernel<<<NTOK / 4, 256, 0, stream>>>(xres, ln2_s, ln2_b, y1);
  // MLP
  gemm_kernel<2><<<dim3(16, 32), 256, 0, stream>>>(y1, w1T, NTOK, 2048, 512, nullptr, b1, h1);
  gemm_kernel<3><<<dim3(4, 32), 256, 0, stream>>>(h1, w2T, NTOK, 512, 2048, xres, b2, (float*)d_out);
}

// Round 4
// 162.233 us; speedup vs baseline: 1.5637x; 1.1378x over previous
//
#include <hip/hip_runtime.h>
#include <hip/hip_bf16.h>

typedef __attribute__((ext_vector_type(4))) float f32x4;
typedef __bf16 bf16x8 __attribute__((ext_vector_type(8)));
using bf16 = __hip_bfloat16;

typedef __attribute__((address_space(1))) const void* gptr_t;
typedef __attribute__((address_space(3))) void* lptr_t;

// Problem constants
constexpr int BB = 2, SS = 2048, DDIM = 512, NHEAD = 8, HDIM = 64, MLPD = 2048;
constexpr int NTOK = BB * SS;          // 4096
constexpr int WHALF = 256;             // window // 2
constexpr int NGLOB = 64;
constexpr float NEGBIG = -1e10f;

// Workspace layout (bytes)
constexpr size_t SZ_X1    = (size_t)NTOK * DDIM * 2;
constexpr size_t SZ_WQKVT = (size_t)1536 * DDIM * 2;
constexpr size_t SZ_WOT   = (size_t)DDIM * DDIM * 2;
constexpr size_t SZ_W1T   = (size_t)MLPD * DDIM * 2;
constexpr size_t SZ_W2T   = (size_t)DDIM * MLPD * 2;
constexpr size_t SZ_HEAD  = (size_t)BB * NHEAD * SS * HDIM * 2;
constexpr size_t SZ_QKV   = 3 * SZ_HEAD;
constexpr size_t SZ_CTX   = (size_t)NTOK * DDIM * 2;
constexpr size_t SZ_XRES  = (size_t)NTOK * DDIM * 4;
constexpr size_t SZ_Y1    = (size_t)NTOK * DDIM * 2;
constexpr size_t SZ_H1    = (size_t)NTOK * MLPD * 2;

constexpr size_t OFF_X1    = 0;
constexpr size_t OFF_WQKVT = OFF_X1 + SZ_X1;
constexpr size_t OFF_WOT   = OFF_WQKVT + SZ_WQKVT;
constexpr size_t OFF_W1T   = OFF_WOT + SZ_WOT;
constexpr size_t OFF_W2T   = OFF_W1T + SZ_W1T;
constexpr size_t OFF_QKV   = OFF_W2T + SZ_W2T;
constexpr size_t OFF_CTX   = OFF_QKV + SZ_QKV;
constexpr size_t OFF_XRES  = OFF_CTX + SZ_CTX;
constexpr size_t OFF_Y1    = OFF_XRES + SZ_XRES;
constexpr size_t OFF_H1    = OFF_Y1 + SZ_Y1;
constexpr size_t OFF_GACC  = OFF_H1 + SZ_H1;                        // [256][16][64] f32
constexpr size_t OFF_GM    = OFF_GACC + (size_t)256 * 16 * 64 * 4;  // [256][16] f32
constexpr size_t OFF_GL    = OFF_GM + (size_t)256 * 16 * 4;         // [256][16] f32

// ---------------------------------------------------------------------------
// Transpose + cast fp32 [K][N] -> bf16 [N][K], with scale.
// ---------------------------------------------------------------------------
__global__ void transpose_cast_kernel(const float* __restrict__ in, bf16* __restrict__ out,
                                      int K, int N, float scale) {
  __shared__ __align__(16) bf16 tile[64][65];
  int k0 = blockIdx.y * 64;
  int n0 = blockIdx.x * 64;
  int t = threadIdx.x;
  for (int it = 0; it < 16; ++it) {
    int idx = it * 256 + t;
    int r = idx >> 6, c = idx & 63;
    float v = in[(size_t)(k0 + r) * N + n0 + c] * scale;
    tile[c][r] = __float2bfloat16(v);
  }
  __syncthreads();
  for (int it = 0; it < 16; ++it) {
    int idx = it * 256 + t;
    int r = idx >> 6, c = idx & 63;
    out[(size_t)(n0 + r) * K + k0 + c] = tile[r][c];
  }
}

// ---------------------------------------------------------------------------
// LayerNorm (fp32 in) -> bf16 out. One wave per 512-el row.
// ---------------------------------------------------------------------------
__global__ void ln_kernel(const float* __restrict__ x, const float* __restrict__ sc,
                          const float* __restrict__ bi, bf16* __restrict__ out) {
  int wv = threadIdx.x >> 6;
  int lane = threadIdx.x & 63;
  int row = blockIdx.x * 4 + wv;
  const float* xr = x + (size_t)row * DDIM + lane * 8;
  float4 v0 = *(const float4*)(xr);
  float4 v1 = *(const float4*)(xr + 4);
  float vv[8] = {v0.x, v0.y, v0.z, v0.w, v1.x, v1.y, v1.z, v1.w};
  float s = 0.f;
  for (int i = 0; i < 8; ++i) s += vv[i];
  for (int m = 1; m < 64; m <<= 1) s += __shfl_xor(s, m, 64);
  float mean = s * (1.0f / DDIM);
  float vs = 0.f;
  for (int i = 0; i < 8; ++i) { float d = vv[i] - mean; vs += d * d; }
  for (int m = 1; m < 64; m <<= 1) vs += __shfl_xor(vs, m, 64);
  float rstd = rsqrtf(vs * (1.0f / DDIM) + 1e-6f);
  __align__(16) bf16 ov[8];
  int c0 = lane * 8;
  for (int i = 0; i < 8; ++i) {
    float y = (vv[i] - mean) * rstd * sc[c0 + i] + bi[c0 + i];
    ov[i] = __float2bfloat16(y);
  }
  *(uint4*)(&out[(size_t)row * DDIM + c0]) = *(const uint4*)ov;
}

// ---------------------------------------------------------------------------
// GEMM m97-style: C[M][N] = A[M][K] x BT[N][K], bf16, BK=64.
// global_load_lds width-16 staging, linear LDS + XOR-swizzled source/read.
// LDS[row][slot] (slot = 16B block of 8 bf16) holds global colblock slot^(row&7).
// ---------------------------------------------------------------------------
template <int BM, int BN, int EPI>
__global__ __launch_bounds__(256, 3)
void gemm_kernel(const bf16* __restrict__ A, const bf16* __restrict__ BT,
                 int M, int N, int K,
                 const float* __restrict__ ep_add, const float* __restrict__ ep_bias,
                 void* __restrict__ out0) {
  constexpr int AM = BM / 32;      // m-fragments per wave (wave tile = BM/2 x BN/2)
  constexpr int AN = BN / 32;      // n-fragments per wave
  constexpr int CHA = BM / 8;      // 1KB staging chunks for A (8 rows each)
  constexpr int CHB = BN / 8;
  __shared__ __align__(16) bf16 As[BM][64];
  __shared__ __align__(16) bf16 Bs[BN][64];
  int t = threadIdx.x;
  int wv = t >> 6, lane = t & 63;
  int wr = wv >> 1, wc = wv & 1;
  int g = lane >> 4, lr = lane & 15;
  int m0 = blockIdx.y * BM, n0 = blockIdx.x * BN;
  int sub_r = lane >> 3;           // 0..7 : row within chunk
  int sub_s = lane & 7;            // 0..7 : 16B slot within row
  f32x4 acc[AM][AN] = {};
  for (int k0 = 0; k0 < K; k0 += 64) {
    __syncthreads();
    // stage A
    for (int c = wv * (CHA / 4); c < (wv + 1) * (CHA / 4); ++c) {
      int row = c * 8 + sub_r;
      int cb = sub_s ^ (row & 7);  // pre-swizzled global source
      const void* src = &A[(size_t)(m0 + row) * K + k0 + cb * 8];
      __builtin_amdgcn_global_load_lds((gptr_t)src,
          (lptr_t)((__attribute__((address_space(3))) char*)(&As[0][0]) + c * 1024), 16, 0, 0);
    }
    // stage B
    for (int c = wv * (CHB / 4); c < (wv + 1) * (CHB / 4); ++c) {
      int row = c * 8 + sub_r;
      int cb = sub_s ^ (row & 7);
      const void* src = &BT[(size_t)(n0 + row) * K + k0 + cb * 8];
      __builtin_amdgcn_global_load_lds((gptr_t)src,
          (lptr_t)((__attribute__((address_space(3))) char*)(&Bs[0][0]) + c * 1024), 16, 0, 0);
    }
    __syncthreads();   // drains vmcnt(0): staged data visible
    const char* Ab = (const char*)&As[0][0];
    const char* Bb = (const char*)&Bs[0][0];
    for (int h = 0; h < 2; ++h) {            // two K=32 halves of the BK=64 tile
      bf16x8 af[AM], bfr[AN];
      for (int i = 0; i < AM; ++i) {
        int row = wr * (BM / 2) + i * 16 + lr;
        int sl = (h * 4 + g) ^ (row & 7);
        af[i] = *(const bf16x8*)(Ab + row * 128 + sl * 16);
      }
      for (int j = 0; j < AN; ++j) {
        int row = wc * (BN / 2) + j * 16 + lr;
        int sl = (h * 4 + g) ^ (row & 7);
        bfr[j] = *(const bf16x8*)(Bb + row * 128 + sl * 16);
      }
      for (int i = 0; i < AM; ++i)
        for (int j = 0; j < AN; ++j)
          acc[i][j] = __builtin_amdgcn_mfma_f32_16x16x32_bf16(af[i], bfr[j], acc[i][j], 0, 0, 0);
    }
  }
  for (int i = 0; i < AM; ++i)
    for (int j = 0; j < AN; ++j)
      for (int r = 0; r < 4; ++r) {
        int m = m0 + wr * (BM / 2) + i * 16 + g * 4 + r;
        int n = n0 + wc * (BN / 2) + j * 16 + lr;
        float val = acc[i][j][r];
        if constexpr (EPI == 0) {
          bf16* qkv = (bf16*)out0;
          int which = n >> 9;
          int hh = (n >> 6) & 7;
          int hd = n & 63;
          int b = m >> 11, sTok = m & 2047;
          size_t off;
          if (which == 2) {
            off = (size_t)2 * (BB * NHEAD * SS * HDIM) +
                  ((size_t)(b * NHEAD + hh) * HDIM + hd) * SS + sTok;
          } else {
            off = (size_t)which * (BB * NHEAD * SS * HDIM) +
                  ((size_t)(b * NHEAD + hh) * SS + sTok) * HDIM + hd;
          }
          qkv[off] = __float2bfloat16(val);
        } else if constexpr (EPI == 1) {
          ((float*)out0)[(size_t)m * N + n] = val + ep_add[(size_t)m * N + n];
        } else if constexpr (EPI == 2) {
          float xb = val + ep_bias[n];
          float inner = 0.7978845608028654f * (xb + 0.044715f * xb * xb * xb);
          float ge = 0.5f * xb * (1.0f + tanhf(inner));
          ((bf16*)out0)[(size_t)m * N + n] = __float2bfloat16(ge);
        } else {
          ((float*)out0)[(size_t)m * N + n] = val + ep_bias[n] + ep_add[(size_t)m * N + n];
        }
      }
}

// ---------------------------------------------------------------------------
// Block-sparse flash attention v3 (unchanged from round 3).
// ---------------------------------------------------------------------------
template <bool MASK>
__device__ __forceinline__ void attn_tile(
    int kb, int qq0, int g, int lr,
    const bf16* __restrict__ Kh, const bf16* __restrict__ VTh,
    const bf16x8& aq0, const bf16x8& aq1,
    float* mrun, float* lsum, f32x4* accO, bf16 (*Plds)[40]) {
  bf16x8 kf0a = *(const bf16x8*)&Kh[(size_t)(kb + lr) * HDIM + g * 8];
  bf16x8 kf0b = *(const bf16x8*)&Kh[(size_t)(kb + lr) * HDIM + 32 + g * 8];
  bf16x8 kf1a = *(const bf16x8*)&Kh[(size_t)(kb + 16 + lr) * HDIM + g * 8];
  bf16x8 kf1b = *(const bf16x8*)&Kh[(size_t)(kb + 16 + lr) * HDIM + 32 + g * 8];
  bf16x8 vf0 = *(const bf16x8*)&VTh[(size_t)(0 * 16 + lr) * SS + kb + g * 8];
  bf16x8 vf1 = *(const bf16x8*)&VTh[(size_t)(1 * 16 + lr) * SS + kb + g * 8];
  bf16x8 vf2 = *(const bf16x8*)&VTh[(size_t)(2 * 16 + lr) * SS + kb + g * 8];
  bf16x8 vf3 = *(const bf16x8*)&VTh[(size_t)(3 * 16 + lr) * SS + kb + g * 8];
  f32x4 s0 = {}, s1 = {};
  s0 = __builtin_amdgcn_mfma_f32_16x16x32_bf16(aq0, kf0a, s0, 0, 0, 0);
  s0 = __builtin_amdgcn_mfma_f32_16x16x32_bf16(aq1, kf0b, s0, 0, 0, 0);
  s1 = __builtin_amdgcn_mfma_f32_16x16x32_bf16(aq0, kf1a, s1, 0, 0, 0);
  s1 = __builtin_amdgcn_mfma_f32_16x16x32_bf16(aq1, kf1b, s1, 0, 0, 0);
  float p0[4], p1[4], tmax[4];
  for (int r = 0; r < 4; ++r) {
    if constexpr (MASK) {
      int i = qq0 + g * 4 + r;
      int d0 = i - (kb + lr), d1 = i - (kb + 16 + lr);
      bool ok0 = (unsigned)(d0 + WHALF) <= 2u * WHALF;
      bool ok1 = (unsigned)(d1 + WHALF) <= 2u * WHALF;
      p0[r] = ok0 ? s0[r] : NEGBIG;
      p1[r] = ok1 ? s1[r] : NEGBIG;
    } else {
      p0[r] = s0[r];
      p1[r] = s1[r];
    }
    tmax[r] = fmaxf(p0[r], p1[r]);
  }
  for (int m = 1; m < 16; m <<= 1)
    for (int r = 0; r < 4; ++r) tmax[r] = fmaxf(tmax[r], __shfl_xor(tmax[r], m, 64));
  float rowsum[4];
  for (int r = 0; r < 4; ++r) {
    float mnew = fmaxf(mrun[r], tmax[r]);
    float resc = __expf(mrun[r] - mnew);
    mrun[r] = mnew;
    lsum[r] *= resc;
    for (int dc = 0; dc < 4; ++dc) accO[dc][r] *= resc;
    p0[r] = __expf(p0[r] - mnew);
    p1[r] = __expf(p1[r] - mnew);
    rowsum[r] = p0[r] + p1[r];
  }
  for (int m = 1; m < 16; m <<= 1)
    for (int r = 0; r < 4; ++r) rowsum[r] += __shfl_xor(rowsum[r], m, 64);
  for (int r = 0; r < 4; ++r) lsum[r] += rowsum[r];
  for (int r = 0; r < 4; ++r) {
    Plds[g * 4 + r][lr] = __float2bfloat16(p0[r]);
    Plds[g * 4 + r][16 + lr] = __float2bfloat16(p1[r]);
  }
  asm volatile("s_waitcnt lgkmcnt(0)" ::: "memory");
  bf16x8 pa = *(const bf16x8*)&Plds[lr][g * 8];
  accO[0] = __builtin_amdgcn_mfma_f32_16x16x32_bf16(pa, vf0, accO[0], 0, 0, 0);
  accO[1] = __builtin_amdgcn_mfma_f32_16x16x32_bf16(pa, vf1, accO[1], 0, 0, 0);
  accO[2] = __builtin_amdgcn_mfma_f32_16x16x32_bf16(pa, vf2, accO[2], 0, 0, 0);
  accO[3] = __builtin_amdgcn_mfma_f32_16x16x32_bf16(pa, vf3, accO[3], 0, 0, 0);
}

constexpr int NBAND = 16 * 124;   // 1984
constexpr int NGSPL = 16 * 4 * 4; // 256
constexpr int NWG   = NBAND + NGSPL; // 2240 (divisible by 8)

__global__ __launch_bounds__(64, 4)
void attn_kernel(const bf16* __restrict__ Qb, const bf16* __restrict__ Kb,
                 const bf16* __restrict__ VTb, bf16* __restrict__ ctx,
                 float* __restrict__ gacc, float* __restrict__ gm,
                 float* __restrict__ gl) {
  __shared__ __align__(16) bf16 Plds[16][40];
  int lane = threadIdx.x;
  int g = lane >> 4, lr = lane & 15;
  int bid = blockIdx.x;
  int swz = (bid & 7) * (NWG / 8) + (bid >> 3);
  float mrun[4], lsum[4];
  f32x4 accO[4] = {};
  for (int r = 0; r < 4; ++r) { mrun[r] = -3e38f; lsum[r] = 0.f; }
  if (swz < NBAND) {
    int bh = swz / 124;
    int qq0 = ((swz % 124) + 4) * 16;   // 64..2032
    int b = bh >> 3, h = bh & 7;
    const bf16* Qh = Qb + (size_t)bh * SS * HDIM;
    const bf16* Kh = Kb + (size_t)bh * SS * HDIM;
    const bf16* VTh = VTb + (size_t)bh * HDIM * SS;
    int qrow = qq0 + lr;
    bf16x8 aq0 = *(const bf16x8*)&Qh[(size_t)qrow * HDIM + g * 8];
    bf16x8 aq1 = *(const bf16x8*)&Qh[(size_t)qrow * HDIM + 32 + g * 8];
    attn_tile<false>(0, qq0, g, lr, Kh, VTh, aq0, aq1, mrun, lsum, accO, Plds);
    attn_tile<false>(32, qq0, g, lr, Kh, VTh, aq0, aq1, mrun, lsum, accO, Plds);
    int blo = qq0 - WHALF;
    int bs = (blo < NGLOB) ? NGLOB : (blo & ~31);
    int bhi = qq0 + 15 + WHALF;
    int be = (bhi + 1 < SS) ? (bhi + 1) : SS;
    for (int kb = bs; kb < be; kb += 32)
      attn_tile<true>(kb, qq0, g, lr, Kh, VTh, aq0, aq1, mrun, lsum, accO, Plds);
    for (int dc = 0; dc < 4; ++dc)
      for (int r = 0; r < 4; ++r) {
        int m = b * SS + qq0 + g * 4 + r;
        int col = h * HDIM + dc * 16 + lr;
        ctx[(size_t)m * DDIM + col] = __float2bfloat16(accO[dc][r] / lsum[r]);
      }
  } else {
    int gidx = swz - NBAND;
    int bh = gidx >> 4, qt = (gidx >> 2) & 3, sp = gidx & 3;
    int qq0 = qt * 16;
    const bf16* Qh = Qb + (size_t)bh * SS * HDIM;
    const bf16* Kh = Kb + (size_t)bh * SS * HDIM;
    const bf16* VTh = VTb + (size_t)bh * HDIM * SS;
    int qrow = qq0 + lr;
    bf16x8 aq0 = *(const bf16x8*)&Qh[(size_t)qrow * HDIM + g * 8];
    bf16x8 aq1 = *(const bf16x8*)&Qh[(size_t)qrow * HDIM + 32 + g * 8];
    int k0 = sp * (SS / 4);
    for (int kb = k0; kb < k0 + SS / 4; kb += 32)
      attn_tile<false>(kb, qq0, g, lr, Kh, VTh, aq0, aq1, mrun, lsum, accO, Plds);
    int grp = (bh * 4 + qt) * 4 + sp;
    for (int dc = 0; dc < 4; ++dc)
      for (int r = 0; r < 4; ++r)
        gacc[((size_t)grp * 16 + g * 4 + r) * 64 + dc * 16 + lr] = accO[dc][r];
    if (lr == 0)
      for (int r = 0; r < 4; ++r) {
        gm[grp * 16 + g * 4 + r] = mrun[r];
        gl[grp * 16 + g * 4 + r] = lsum[r];
      }
  }
}

__global__ __launch_bounds__(64, 4)
void attn_combine_kernel(const float* __restrict__ gacc, const float* __restrict__ gm,
                         const float* __restrict__ gl, bf16* __restrict__ ctx) {
  int grp4 = blockIdx.x;          // bh*4 + qt
  int bh = grp4 >> 2, qt = grp4 & 3;
  int b = bh >> 3, h = bh & 7;
  int c = threadIdx.x;
  for (int r = 0; r < 16; ++r) {
    float ms[4], M = -3e38f;
    for (int s2 = 0; s2 < 4; ++s2) {
      ms[s2] = gm[(grp4 * 4 + s2) * 16 + r];
      M = fmaxf(M, ms[s2]);
    }
    float L = 0.f, val = 0.f;
    for (int s2 = 0; s2 < 4; ++s2) {
      float w = __expf(ms[s2] - M);
      L += gl[(grp4 * 4 + s2) * 16 + r] * w;
      val += gacc[((size_t)(grp4 * 4 + s2) * 16 + r) * 64 + c] * w;
    }
    ctx[(size_t)(b * SS + qt * 16 + r) * DDIM + h * HDIM + c] = __float2bfloat16(val / L);
  }
}

// ---------------------------------------------------------------------------
extern "C" void kernel_launch(void* const* d_in, const int* in_sizes, int n_in,
                              void* d_out, int out_size, void* d_ws, size_t ws_size,
                              hipStream_t stream) {
  const float* inputs = (const float*)d_in[0];
  const float* ln1_s = (const float*)d_in[2];
  const float* ln1_b = (const float*)d_in[3];
  const float* wq = (const float*)d_in[4];
  const float* wk = (const float*)d_in[5];
  const float* wv = (const float*)d_in[6];
  const float* wo = (const float*)d_in[7];
  const float* ln2_s = (const float*)d_in[8];
  const float* ln2_b = (const float*)d_in[9];
  const float* w1 = (const float*)d_in[10];
  const float* b1 = (const float*)d_in[11];
  const float* w2 = (const float*)d_in[12];
  const float* b2 = (const float*)d_in[13];

  char* ws = (char*)d_ws;
  bf16* x1    = (bf16*)(ws + OFF_X1);
  bf16* wqkvT = (bf16*)(ws + OFF_WQKVT);
  bf16* woT   = (bf16*)(ws + OFF_WOT);
  bf16* w1T   = (bf16*)(ws + OFF_W1T);
  bf16* w2T   = (bf16*)(ws + OFF_W2T);
  bf16* qkv   = (bf16*)(ws + OFF_QKV);
  bf16* ctx   = (bf16*)(ws + OFF_CTX);
  float* xres = (float*)(ws + OFF_XRES);
  bf16* y1    = (bf16*)(ws + OFF_Y1);
  bf16* h1    = (bf16*)(ws + OFF_H1);
  float* gacc = (float*)(ws + OFF_GACC);
  float* gm   = (float*)(ws + OFF_GM);
  float* gl   = (float*)(ws + OFF_GL);
  size_t headsz = (size_t)BB * NHEAD * SS * HDIM;

  // Weight prep (fold 1/sqrt(64) into wq)
  transpose_cast_kernel<<<dim3(8, 8), 256, 0, stream>>>(wq, wqkvT, 512, 512, 0.125f);
  transpose_cast_kernel<<<dim3(8, 8), 256, 0, stream>>>(wk, wqkvT + (size_t)512 * 512, 512, 512, 1.f);
  transpose_cast_kernel<<<dim3(8, 8), 256, 0, stream>>>(wv, wqkvT + (size_t)1024 * 512, 512, 512, 1.f);
  transpose_cast_kernel<<<dim3(8, 8), 256, 0, stream>>>(wo, woT, 512, 512, 1.f);
  transpose_cast_kernel<<<dim3(32, 8), 256, 0, stream>>>(w1, w1T, 512, 2048, 1.f);
  transpose_cast_kernel<<<dim3(8, 32), 256, 0, stream>>>(w2, w2T, 2048, 512, 1.f);

  // LN1
  ln_kernel<<<NTOK / 4, 256, 0, stream>>>(inputs, ln1_s, ln1_b, x1);
  // QKV projection (V written transposed)
  gemm_kernel<128, 128, 0><<<dim3(12, 32), 256, 0, stream>>>(x1, wqkvT, NTOK, 1536, 512, nullptr, nullptr, qkv);
  // Attention (band + global-split), then combine
  attn_kernel<<<NWG, 64, 0, stream>>>(qkv, qkv + headsz, qkv + 2 * headsz, ctx, gacc, gm, gl);
  attn_combine_kernel<<<64, 64, 0, stream>>>(gacc, gm, gl, ctx);
  // Output projection + residual (BN=64 -> 256 wgs)
  gemm_kernel<128, 64, 1><<<dim3(8, 32), 256, 0, stream>>>(ctx, woT, NTOK, 512, 512, inputs, nullptr, xres);
  // LN2
  ln_kernel<<<NTOK / 4, 256, 0, stream>>>(xres, ln2_s, ln2_b, y1);
  // MLP
  gemm_kernel<128, 128, 2><<<dim3(16, 32), 256, 0, stream>>>(y1, w1T, NTOK, 2048, 512, nullptr, b1, h1);
  gemm_kernel<128, 64, 3><<<dim3(8, 32), 256, 0, stream>>>(h1, w2T, NTOK, 512, 2048, xres, b2, (float*)d_out);
}

// Round 5
// 151.265 us; speedup vs baseline: 1.6771x; 1.0725x over previous
//
#include <hip/hip_runtime.h>
#include <hip/hip_bf16.h>

typedef __attribute__((ext_vector_type(4))) float f32x4;
typedef __bf16 bf16x8 __attribute__((ext_vector_type(8)));
using bf16 = __hip_bfloat16;

typedef __attribute__((address_space(1))) const void* gptr_t;
typedef __attribute__((address_space(3))) void* lptr_t;
typedef __attribute__((address_space(3))) char* lchar_t;

// Problem constants
constexpr int BB = 2, SS = 2048, DDIM = 512, NHEAD = 8, HDIM = 64, MLPD = 2048;
constexpr int NTOK = BB * SS;          // 4096
constexpr int WHALF = 256;             // window // 2
constexpr int NGLOB = 64;
constexpr float NEGBIG = -1e10f;

// Workspace layout (bytes)
constexpr size_t SZ_X1    = (size_t)NTOK * DDIM * 2;
constexpr size_t SZ_WQKVT = (size_t)1536 * DDIM * 2;
constexpr size_t SZ_WOT   = (size_t)DDIM * DDIM * 2;
constexpr size_t SZ_W1T   = (size_t)MLPD * DDIM * 2;
constexpr size_t SZ_W2T   = (size_t)DDIM * MLPD * 2;
constexpr size_t SZ_HEAD  = (size_t)BB * NHEAD * SS * HDIM * 2;
constexpr size_t SZ_QKV   = 3 * SZ_HEAD;
constexpr size_t SZ_CTX   = (size_t)NTOK * DDIM * 2;
constexpr size_t SZ_XRES  = (size_t)NTOK * DDIM * 4;
constexpr size_t SZ_Y1    = (size_t)NTOK * DDIM * 2;
constexpr size_t SZ_H1    = (size_t)NTOK * MLPD * 2;

constexpr size_t OFF_X1    = 0;
constexpr size_t OFF_WQKVT = OFF_X1 + SZ_X1;
constexpr size_t OFF_WOT   = OFF_WQKVT + SZ_WQKVT;
constexpr size_t OFF_W1T   = OFF_WOT + SZ_WOT;
constexpr size_t OFF_W2T   = OFF_W1T + SZ_W1T;
constexpr size_t OFF_QKV   = OFF_W2T + SZ_W2T;
constexpr size_t OFF_CTX   = OFF_QKV + SZ_QKV;
constexpr size_t OFF_XRES  = OFF_CTX + SZ_CTX;
constexpr size_t OFF_Y1    = OFF_XRES + SZ_XRES;
constexpr size_t OFF_H1    = OFF_Y1 + SZ_Y1;
constexpr size_t OFF_GACC  = OFF_H1 + SZ_H1;                        // [256][16][64] f32
constexpr size_t OFF_GM    = OFF_GACC + (size_t)256 * 16 * 64 * 4;  // [256][16] f32
constexpr size_t OFF_GL    = OFF_GM + (size_t)256 * 16 * 4;         // [256][16] f32

// ---------------------------------------------------------------------------
// Transpose + cast fp32 [K][N] -> bf16 [N][K], with scale.
// ---------------------------------------------------------------------------
__global__ void transpose_cast_kernel(const float* __restrict__ in, bf16* __restrict__ out,
                                      int K, int N, float scale) {
  __shared__ __align__(16) bf16 tile[64][65];
  int k0 = blockIdx.y * 64;
  int n0 = blockIdx.x * 64;
  int t = threadIdx.x;
  for (int it = 0; it < 16; ++it) {
    int idx = it * 256 + t;
    int r = idx >> 6, c = idx & 63;
    float v = in[(size_t)(k0 + r) * N + n0 + c] * scale;
    tile[c][r] = __float2bfloat16(v);
  }
  __syncthreads();
  for (int it = 0; it < 16; ++it) {
    int idx = it * 256 + t;
    int r = idx >> 6, c = idx & 63;
    out[(size_t)(n0 + r) * K + k0 + c] = tile[r][c];
  }
}

// ---------------------------------------------------------------------------
// LayerNorm (fp32 in) -> bf16 out. One wave per 512-el row.
// ---------------------------------------------------------------------------
__global__ void ln_kernel(const float* __restrict__ x, const float* __restrict__ sc,
                          const float* __restrict__ bi, bf16* __restrict__ out) {
  int wv = threadIdx.x >> 6;
  int lane = threadIdx.x & 63;
  int row = blockIdx.x * 4 + wv;
  const float* xr = x + (size_t)row * DDIM + lane * 8;
  float4 v0 = *(const float4*)(xr);
  float4 v1 = *(const float4*)(xr + 4);
  float vv[8] = {v0.x, v0.y, v0.z, v0.w, v1.x, v1.y, v1.z, v1.w};
  float s = 0.f;
  for (int i = 0; i < 8; ++i) s += vv[i];
  for (int m = 1; m < 64; m <<= 1) s += __shfl_xor(s, m, 64);
  float mean = s * (1.0f / DDIM);
  float vs = 0.f;
  for (int i = 0; i < 8; ++i) { float d = vv[i] - mean; vs += d * d; }
  for (int m = 1; m < 64; m <<= 1) vs += __shfl_xor(vs, m, 64);
  float rstd = rsqrtf(vs * (1.0f / DDIM) + 1e-6f);
  __align__(16) bf16 ov[8];
  int c0 = lane * 8;
  for (int i = 0; i < 8; ++i) {
    float y = (vv[i] - mean) * rstd * sc[c0 + i] + bi[c0 + i];
    ov[i] = __float2bfloat16(y);
  }
  *(uint4*)(&out[(size_t)row * DDIM + c0]) = *(const uint4*)ov;
}

// ---------------------------------------------------------------------------
// GEMM v3: double-buffered LDS, global_load_lds staging, T3-minimum 2-phase:
//   stage(0); vmcnt(0); barrier;
//   loop: stage(t+1); compute(t); vmcnt(0); barrier;
// XOR-swizzled source/read (linear LDS dest), 1D XCD-swizzled grid.
// ---------------------------------------------------------------------------
template <int BM, int BN, int EPI>
__global__ __launch_bounds__(256, 2)
void gemm_kernel(const bf16* __restrict__ A, const bf16* __restrict__ BT,
                 int M, int N, int K, int gx,
                 const float* __restrict__ ep_add, const float* __restrict__ ep_bias,
                 void* __restrict__ out0) {
  constexpr int AM = BM / 32;      // m-frags per wave (wave tile BM/2 x BN/2)
  constexpr int AN = BN / 32;
  constexpr int CA4 = (BM / 8) / 4;  // A chunks per wave
  constexpr int CB4 = (BN / 8) / 4;
  __shared__ __align__(16) bf16 As[2][BM][64];
  __shared__ __align__(16) bf16 Bs[2][BN][64];
  int t = threadIdx.x;
  int wv = t >> 6, lane = t & 63;
  int wr = wv >> 1, wc = wv & 1;
  int g = lane >> 4, lr = lane & 15;
  int sub_r = lane >> 3, sub_s = lane & 7;
  int nwg = gridDim.x;
  int bid = blockIdx.x;
  int swz = (bid & 7) * (nwg >> 3) + (bid >> 3);
  int m0 = (swz / gx) * BM;
  int n0 = (swz % gx) * BN;
  lchar_t asA = (lchar_t)&As[0][0][0];
  lchar_t asB = (lchar_t)&Bs[0][0][0];

  auto stage = [&](int kt, int bb) {
    int k0 = kt * 64;
#pragma unroll
    for (int i = 0; i < CA4; ++i) {
      int c = wv + 4 * i;
      int row = c * 8 + sub_r;
      int cb = sub_s ^ (row & 7);
      __builtin_amdgcn_global_load_lds(
          (gptr_t)&A[(size_t)(m0 + row) * K + k0 + cb * 8],
          (lptr_t)(asA + bb * (BM * 128) + c * 1024), 16, 0, 0);
    }
#pragma unroll
    for (int i = 0; i < CB4; ++i) {
      int c = wv + 4 * i;
      int row = c * 8 + sub_r;
      int cb = sub_s ^ (row & 7);
      __builtin_amdgcn_global_load_lds(
          (gptr_t)&BT[(size_t)(n0 + row) * K + k0 + cb * 8],
          (lptr_t)(asB + bb * (BN * 128) + c * 1024), 16, 0, 0);
    }
  };

  f32x4 acc[AM][AN] = {};
  int NT = K >> 6;
  stage(0, 0);
  asm volatile("s_waitcnt vmcnt(0)" ::: "memory");
  __builtin_amdgcn_s_barrier();
  __builtin_amdgcn_sched_barrier(0);
  for (int kt = 0; kt < NT; ++kt) {
    int bb = kt & 1;
    if (kt + 1 < NT) stage(kt + 1, bb ^ 1);
    const char* Ab = (const char*)&As[bb][0][0];
    const char* Bb = (const char*)&Bs[bb][0][0];
#pragma unroll
    for (int h = 0; h < 2; ++h) {
      bf16x8 af[AM], bfr[AN];
#pragma unroll
      for (int i = 0; i < AM; ++i) {
        int row = wr * (BM / 2) + i * 16 + lr;
        int sl = (h * 4 + g) ^ (row & 7);
        af[i] = *(const bf16x8*)(Ab + row * 128 + sl * 16);
      }
#pragma unroll
      for (int j = 0; j < AN; ++j) {
        int row = wc * (BN / 2) + j * 16 + lr;
        int sl = (h * 4 + g) ^ (row & 7);
        bfr[j] = *(const bf16x8*)(Bb + row * 128 + sl * 16);
      }
#pragma unroll
      for (int i = 0; i < AM; ++i)
#pragma unroll
        for (int j = 0; j < AN; ++j)
          acc[i][j] = __builtin_amdgcn_mfma_f32_16x16x32_bf16(af[i], bfr[j], acc[i][j], 0, 0, 0);
    }
    asm volatile("s_waitcnt vmcnt(0)" ::: "memory");
    __builtin_amdgcn_s_barrier();
    __builtin_amdgcn_sched_barrier(0);
  }
#pragma unroll
  for (int i = 0; i < AM; ++i)
#pragma unroll
    for (int j = 0; j < AN; ++j)
#pragma unroll
      for (int r = 0; r < 4; ++r) {
        int m = m0 + wr * (BM / 2) + i * 16 + g * 4 + r;
        int n = n0 + wc * (BN / 2) + j * 16 + lr;
        float val = acc[i][j][r];
        if constexpr (EPI == 0) {
          bf16* qkv = (bf16*)out0;
          int which = n >> 9;
          int hh = (n >> 6) & 7;
          int hd = n & 63;
          int b = m >> 11, sTok = m & 2047;
          size_t off;
          if (which == 2) {
            off = (size_t)2 * (BB * NHEAD * SS * HDIM) +
                  ((size_t)(b * NHEAD + hh) * HDIM + hd) * SS + sTok;
          } else {
            off = (size_t)which * (BB * NHEAD * SS * HDIM) +
                  ((size_t)(b * NHEAD + hh) * SS + sTok) * HDIM + hd;
          }
          qkv[off] = __float2bfloat16(val);
        } else if constexpr (EPI == 1) {
          ((float*)out0)[(size_t)m * N + n] = val + ep_add[(size_t)m * N + n];
        } else if constexpr (EPI == 2) {
          float xb = val + ep_bias[n];
          float inner = 0.7978845608028654f * (xb + 0.044715f * xb * xb * xb);
          float ge = 0.5f * xb * (1.0f + tanhf(inner));
          ((bf16*)out0)[(size_t)m * N + n] = __float2bfloat16(ge);
        } else {
          ((float*)out0)[(size_t)m * N + n] = val + ep_bias[n] + ep_add[(size_t)m * N + n];
        }
      }
}

// ---------------------------------------------------------------------------
// Block-sparse flash attention v4: 2 waves per q-tile, KV list split across
// waves (parity interleave), in-LDS online-softmax merge.
// ---------------------------------------------------------------------------
template <bool MASK>
__device__ __forceinline__ void attn_tile(
    int kb, int qq0, int g, int lr,
    const bf16* __restrict__ Kh, const bf16* __restrict__ VTh,
    const bf16x8& aq0, const bf16x8& aq1,
    float* mrun, float* lsum, f32x4* accO, bf16 (*Plds)[40]) {
  bf16x8 kf0a = *(const bf16x8*)&Kh[(size_t)(kb + lr) * HDIM + g * 8];
  bf16x8 kf0b = *(const bf16x8*)&Kh[(size_t)(kb + lr) * HDIM + 32 + g * 8];
  bf16x8 kf1a = *(const bf16x8*)&Kh[(size_t)(kb + 16 + lr) * HDIM + g * 8];
  bf16x8 kf1b = *(const bf16x8*)&Kh[(size_t)(kb + 16 + lr) * HDIM + 32 + g * 8];
  bf16x8 vf0 = *(const bf16x8*)&VTh[(size_t)(0 * 16 + lr) * SS + kb + g * 8];
  bf16x8 vf1 = *(const bf16x8*)&VTh[(size_t)(1 * 16 + lr) * SS + kb + g * 8];
  bf16x8 vf2 = *(const bf16x8*)&VTh[(size_t)(2 * 16 + lr) * SS + kb + g * 8];
  bf16x8 vf3 = *(const bf16x8*)&VTh[(size_t)(3 * 16 + lr) * SS + kb + g * 8];
  f32x4 s0 = {}, s1 = {};
  s0 = __builtin_amdgcn_mfma_f32_16x16x32_bf16(aq0, kf0a, s0, 0, 0, 0);
  s0 = __builtin_amdgcn_mfma_f32_16x16x32_bf16(aq1, kf0b, s0, 0, 0, 0);
  s1 = __builtin_amdgcn_mfma_f32_16x16x32_bf16(aq0, kf1a, s1, 0, 0, 0);
  s1 = __builtin_amdgcn_mfma_f32_16x16x32_bf16(aq1, kf1b, s1, 0, 0, 0);
  float p0[4], p1[4], tmax[4];
  for (int r = 0; r < 4; ++r) {
    if constexpr (MASK) {
      int i = qq0 + g * 4 + r;
      int d0 = i - (kb + lr), d1 = i - (kb + 16 + lr);
      bool ok0 = (unsigned)(d0 + WHALF) <= 2u * WHALF;
      bool ok1 = (unsigned)(d1 + WHALF) <= 2u * WHALF;
      p0[r] = ok0 ? s0[r] : NEGBIG;
      p1[r] = ok1 ? s1[r] : NEGBIG;
    } else {
      p0[r] = s0[r];
      p1[r] = s1[r];
    }
    tmax[r] = fmaxf(p0[r], p1[r]);
  }
  for (int m = 1; m < 16; m <<= 1)
    for (int r = 0; r < 4; ++r) tmax[r] = fmaxf(tmax[r], __shfl_xor(tmax[r], m, 64));
  float rowsum[4];
  for (int r = 0; r < 4; ++r) {
    float mnew = fmaxf(mrun[r], tmax[r]);
    float resc = __expf(mrun[r] - mnew);
    mrun[r] = mnew;
    lsum[r] *= resc;
    for (int dc = 0; dc < 4; ++dc) accO[dc][r] *= resc;
    p0[r] = __expf(p0[r] - mnew);
    p1[r] = __expf(p1[r] - mnew);
    rowsum[r] = p0[r] + p1[r];
  }
  for (int m = 1; m < 16; m <<= 1)
    for (int r = 0; r < 4; ++r) rowsum[r] += __shfl_xor(rowsum[r], m, 64);
  for (int r = 0; r < 4; ++r) lsum[r] += rowsum[r];
  for (int r = 0; r < 4; ++r) {
    Plds[g * 4 + r][lr] = __float2bfloat16(p0[r]);
    Plds[g * 4 + r][16 + lr] = __float2bfloat16(p1[r]);
  }
  asm volatile("s_waitcnt lgkmcnt(0)" ::: "memory");
  bf16x8 pa = *(const bf16x8*)&Plds[lr][g * 8];
  accO[0] = __builtin_amdgcn_mfma_f32_16x16x32_bf16(pa, vf0, accO[0], 0, 0, 0);
  accO[1] = __builtin_amdgcn_mfma_f32_16x16x32_bf16(pa, vf1, accO[1], 0, 0, 0);
  accO[2] = __builtin_amdgcn_mfma_f32_16x16x32_bf16(pa, vf2, accO[2], 0, 0, 0);
  accO[3] = __builtin_amdgcn_mfma_f32_16x16x32_bf16(pa, vf3, accO[3], 0, 0, 0);
}

constexpr int NBAND = 16 * 124;   // 1984
constexpr int NGSPL = 16 * 4 * 4; // 256
constexpr int NWG   = NBAND + NGSPL; // 2240 (divisible by 8)

__global__ __launch_bounds__(128, 4)
void attn_kernel(const bf16* __restrict__ Qb, const bf16* __restrict__ Kb,
                 const bf16* __restrict__ VTb, bf16* __restrict__ ctx,
                 float* __restrict__ gacc, float* __restrict__ gm,
                 float* __restrict__ gl) {
  __shared__ __align__(16) bf16 Plds[2][16][40];
  __shared__ __align__(16) float mAcc[16][68];
  __shared__ float mM[16], mL[16];
  int t = threadIdx.x;
  int w = t >> 6, lane = t & 63;
  int g = lane >> 4, lr = lane & 15;
  int bid = blockIdx.x;
  int swz = (bid & 7) * (NWG / 8) + (bid >> 3);
  float mrun[4], lsum[4];
  f32x4 accO[4] = {};
  for (int r = 0; r < 4; ++r) { mrun[r] = -3e38f; lsum[r] = 0.f; }

  if (swz < NBAND) {
    int bh = swz / 124;
    int qq0 = ((swz % 124) + 4) * 16;   // 64..2032
    int b = bh >> 3, h = bh & 7;
    const bf16* Qh = Qb + (size_t)bh * SS * HDIM;
    const bf16* Kh = Kb + (size_t)bh * SS * HDIM;
    const bf16* VTh = VTb + (size_t)bh * HDIM * SS;
    int qrow = qq0 + lr;
    bf16x8 aq0 = *(const bf16x8*)&Qh[(size_t)qrow * HDIM + g * 8];
    bf16x8 aq1 = *(const bf16x8*)&Qh[(size_t)qrow * HDIM + 32 + g * 8];
    if (w == 0) {
      attn_tile<false>(0, qq0, g, lr, Kh, VTh, aq0, aq1, mrun, lsum, accO, Plds[0]);
      attn_tile<false>(32, qq0, g, lr, Kh, VTh, aq0, aq1, mrun, lsum, accO, Plds[0]);
    }
    int blo = qq0 - WHALF;
    int bs = (blo < NGLOB) ? NGLOB : (blo & ~31);
    int bhi = qq0 + 15 + WHALF;
    int be = (bhi + 1 < SS) ? (bhi + 1) : SS;
    int idx = 0;
    for (int kb = bs; kb < be; kb += 32, ++idx)
      if ((idx & 1) == w)
        attn_tile<true>(kb, qq0, g, lr, Kh, VTh, aq0, aq1, mrun, lsum, accO, Plds[w]);
    // merge wave1 into wave0 via LDS
    if (w == 1) {
      for (int dc = 0; dc < 4; ++dc)
        for (int r = 0; r < 4; ++r) mAcc[g * 4 + r][dc * 16 + lr] = accO[dc][r];
      if (lr == 0)
        for (int r = 0; r < 4; ++r) { mM[g * 4 + r] = mrun[r]; mL[g * 4 + r] = lsum[r]; }
    }
    __syncthreads();
    if (w == 0) {
      for (int r = 0; r < 4; ++r) {
        float m1 = mM[g * 4 + r], l1 = mL[g * 4 + r];
        float M = fmaxf(mrun[r], m1);
        float w0 = __expf(mrun[r] - M), w1 = __expf(m1 - M);
        float L = lsum[r] * w0 + l1 * w1;
        for (int dc = 0; dc < 4; ++dc) {
          float val = (accO[dc][r] * w0 + mAcc[g * 4 + r][dc * 16 + lr] * w1) / L;
          int m = b * SS + qq0 + g * 4 + r;
          int col = h * HDIM + dc * 16 + lr;
          ctx[(size_t)m * DDIM + col] = __float2bfloat16(val);
        }
      }
    }
  } else {
    int gidx = swz - NBAND;
    int bh = gidx >> 4, qt = (gidx >> 2) & 3, sp = gidx & 3;
    int qq0 = qt * 16;                  // <64: global rows, no masking
    const bf16* Qh = Qb + (size_t)bh * SS * HDIM;
    const bf16* Kh = Kb + (size_t)bh * SS * HDIM;
    const bf16* VTh = VTb + (size_t)bh * HDIM * SS;
    int qrow = qq0 + lr;
    bf16x8 aq0 = *(const bf16x8*)&Qh[(size_t)qrow * HDIM + g * 8];
    bf16x8 aq1 = *(const bf16x8*)&Qh[(size_t)qrow * HDIM + 32 + g * 8];
    int k0 = sp * (SS / 4) + w * (SS / 8);
    for (int kb = k0; kb < k0 + SS / 8; kb += 32)
      attn_tile<false>(kb, qq0, g, lr, Kh, VTh, aq0, aq1, mrun, lsum, accO, Plds[w]);
    if (w == 1) {
      for (int dc = 0; dc < 4; ++dc)
        for (int r = 0; r < 4; ++r) mAcc[g * 4 + r][dc * 16 + lr] = accO[dc][r];
      if (lr == 0)
        for (int r = 0; r < 4; ++r) { mM[g * 4 + r] = mrun[r]; mL[g * 4 + r] = lsum[r]; }
    }
    __syncthreads();
    if (w == 0) {
      int grp = (bh * 4 + qt) * 4 + sp;
      for (int r = 0; r < 4; ++r) {
        float m1 = mM[g * 4 + r], l1 = mL[g * 4 + r];
        float M = fmaxf(mrun[r], m1);
        float w0 = __expf(mrun[r] - M), w1 = __expf(m1 - M);
        float L = lsum[r] * w0 + l1 * w1;
        for (int dc = 0; dc < 4; ++dc) {
          float val = accO[dc][r] * w0 + mAcc[g * 4 + r][dc * 16 + lr] * w1;
          gacc[((size_t)grp * 16 + g * 4 + r) * 64 + dc * 16 + lr] = val;
        }
        if (lr == 0) {
          gm[grp * 16 + g * 4 + r] = M;
          gl[grp * 16 + g * 4 + r] = L;
        }
      }
    }
  }
}

// Merge the 4 KV-splits of each global q-tile.
__global__ __launch_bounds__(64, 4)
void attn_combine_kernel(const float* __restrict__ gacc, const float* __restrict__ gm,
                         const float* __restrict__ gl, bf16* __restrict__ ctx) {
  int grp4 = blockIdx.x;          // bh*4 + qt
  int bh = grp4 >> 2, qt = grp4 & 3;
  int b = bh >> 3, h = bh & 7;
  int c = threadIdx.x;
  for (int r = 0; r < 16; ++r) {
    float ms[4], M = -3e38f;
    for (int s2 = 0; s2 < 4; ++s2) {
      ms[s2] = gm[(grp4 * 4 + s2) * 16 + r];
      M = fmaxf(M, ms[s2]);
    }
    float L = 0.f, val = 0.f;
    for (int s2 = 0; s2 < 4; ++s2) {
      float wgt = __expf(ms[s2] - M);
      L += gl[(grp4 * 4 + s2) * 16 + r] * wgt;
      val += gacc[((size_t)(grp4 * 4 + s2) * 16 + r) * 64 + c] * wgt;
    }
    ctx[(size_t)(b * SS + qt * 16 + r) * DDIM + h * HDIM + c] = __float2bfloat16(val / L);
  }
}

// ---------------------------------------------------------------------------
extern "C" void kernel_launch(void* const* d_in, const int* in_sizes, int n_in,
                              void* d_out, int out_size, void* d_ws, size_t ws_size,
                              hipStream_t stream) {
  const float* inputs = (const float*)d_in[0];
  const float* ln1_s = (const float*)d_in[2];
  const float* ln1_b = (const float*)d_in[3];
  const float* wq = (const float*)d_in[4];
  const float* wk = (const float*)d_in[5];
  const float* wv = (const float*)d_in[6];
  const float* wo = (const float*)d_in[7];
  const float* ln2_s = (const float*)d_in[8];
  const float* ln2_b = (const float*)d_in[9];
  const float* w1 = (const float*)d_in[10];
  const float* b1 = (const float*)d_in[11];
  const float* w2 = (const float*)d_in[12];
  const float* b2 = (const float*)d_in[13];

  char* ws = (char*)d_ws;
  bf16* x1    = (bf16*)(ws + OFF_X1);
  bf16* wqkvT = (bf16*)(ws + OFF_WQKVT);
  bf16* woT   = (bf16*)(ws + OFF_WOT);
  bf16* w1T   = (bf16*)(ws + OFF_W1T);
  bf16* w2T   = (bf16*)(ws + OFF_W2T);
  bf16* qkv   = (bf16*)(ws + OFF_QKV);
  bf16* ctx   = (bf16*)(ws + OFF_CTX);
  float* xres = (float*)(ws + OFF_XRES);
  bf16* y1    = (bf16*)(ws + OFF_Y1);
  bf16* h1    = (bf16*)(ws + OFF_H1);
  float* gacc = (float*)(ws + OFF_GACC);
  float* gm   = (float*)(ws + OFF_GM);
  float* gl   = (float*)(ws + OFF_GL);
  size_t headsz = (size_t)BB * NHEAD * SS * HDIM;

  // Weight prep (fold 1/sqrt(64) into wq)
  transpose_cast_kernel<<<dim3(8, 8), 256, 0, stream>>>(wq, wqkvT, 512, 512, 0.125f);
  transpose_cast_kernel<<<dim3(8, 8), 256, 0, stream>>>(wk, wqkvT + (size_t)512 * 512, 512, 512, 1.f);
  transpose_cast_kernel<<<dim3(8, 8), 256, 0, stream>>>(wv, wqkvT + (size_t)1024 * 512, 512, 512, 1.f);
  transpose_cast_kernel<<<dim3(8, 8), 256, 0, stream>>>(wo, woT, 512, 512, 1.f);
  transpose_cast_kernel<<<dim3(32, 8), 256, 0, stream>>>(w1, w1T, 512, 2048, 1.f);
  transpose_cast_kernel<<<dim3(8, 32), 256, 0, stream>>>(w2, w2T, 2048, 512, 1.f);

  // LN1
  ln_kernel<<<NTOK / 4, 256, 0, stream>>>(inputs, ln1_s, ln1_b, x1);
  // QKV projection (V written transposed): M=4096 N=1536 K=512, 64x128 tiles
  gemm_kernel<64, 128, 0><<<12 * 64, 256, 0, stream>>>(x1, wqkvT, NTOK, 1536, 512, 12, nullptr, nullptr, qkv);
  // Attention (band + global-split), then combine
  attn_kernel<<<NWG, 128, 0, stream>>>(qkv, qkv + headsz, qkv + 2 * headsz, ctx, gacc, gm, gl);
  attn_combine_kernel<<<64, 64, 0, stream>>>(gacc, gm, gl, ctx);
  // Output projection + residual: M=4096 N=512 K=512, 64x64 tiles
  gemm_kernel<64, 64, 1><<<8 * 64, 256, 0, stream>>>(ctx, woT, NTOK, 512, 512, 8, inputs, nullptr, xres);
  // LN2
  ln_kernel<<<NTOK / 4, 256, 0, stream>>>(xres, ln2_s, ln2_b, y1);
  // MLP up: M=4096 N=2048 K=512, 64x128 tiles
  gemm_kernel<64, 128, 2><<<16 * 64, 256, 0, stream>>>(y1, w1T, NTOK, 2048, 512, 16, nullptr, b1, h1);
  // MLP down: M=4096 N=512 K=2048, 64x64 tiles
  gemm_kernel<64, 64, 3><<<8 * 64, 256, 0, stream>>>(h1, w2T, NTOK, 512, 2048, 8, xres, b2, (float*)d_out);
}